// Round 3
// baseline (2459.412 us; speedup 1.0000x reference)
//
#include <hip/hip_runtime.h>

typedef unsigned short u16;
typedef unsigned int u32;

#define NN 20000
#define NE 320000

// ---------------- workspace layout (bytes) ----------------
#define WS_FLAG  0         // 1 i32: 1 = inputs are bf16, 0 = inputs are f32
#define WS_H     256       // 640 f32   H[z][c]
#define WS_U1    3072      // 36  f32
#define WS_U2    3328      // 180 f32   U2sym[45][4]
#define WS_U3    4096      // 660 f32   U3sym[165][4]
#define WS_DEG   7168      // 20000 i32
#define WS_CUR   87168     // 20000 i32 (contiguous after DEG; one memset covers both)
#define WS_OFF   167168    // 20000 i32
#define WS_BSUM  247168    // 79 i32
#define WS_BOFF  247552    // 79 i32
#define WS_ELIST 248064    // 320000 i32
#define WS_POSF  1528064   // 20000 float4   (total ~1.85 MB)

__device__ __forceinline__ float bf2f(u16 u){ return __uint_as_float(((u32)u) << 16); }
__device__ __forceinline__ u16 f2bf(float f){
  u32 u = __float_as_uint(f);
  u32 r = (u + 0x7fffu + ((u >> 16) & 1u)) >> 16;
  return (u16)r;
}
__device__ __forceinline__ float bflo(u32 d){ return __uint_as_float(d << 16); }
__device__ __forceinline__ float bfhi(u32 d){ return __uint_as_float(d & 0xffff0000u); }
__device__ __forceinline__ float silu_f(float v){ return v / (1.0f + __expf(-v)); }

// dtype-agnostic float load: bf=1 -> buffer holds bf16 u16, bf=0 -> f32
__device__ __forceinline__ float ldf(const void* p, int i, int bf){
  return bf ? bf2f(((const u16*)p)[i]) : ((const float*)p)[i];
}

// ---------------- dtype sniffer ----------------
// Reads first 256 dwords of W_up (4096 N(0,1) values). If bf16-packed, the low
// u16 of each dword is a bf16 of a normal value -> exponent in [0x60,0x86]
// essentially always. If f32, low u16 = uniform mantissa bits -> ~15% hit rate.
extern "C" __global__ __launch_bounds__(256)
void k_sniff(const u32* __restrict__ wu, int* __restrict__ flag)
{
  __shared__ int s[256];
  int tid = threadIdx.x;
  u32 w = wu[tid];
  u32 e = (w >> 7) & 0xFFu;   // exponent field of the low-half bf16
  s[tid] = (e >= 0x60u && e <= 0x86u) ? 1 : 0;
  __syncthreads();
  for (int d = 128; d > 0; d >>= 1){
    if (tid < d) s[tid] += s[tid + d];
    __syncthreads();
  }
  if (tid == 0) flag[0] = (s[0] > 148) ? 1 : 0;
}

// ---------------- prep: H table + symmetrized U tables ----------------
extern "C" __global__ __launch_bounds__(256)
void k_prep(const void* __restrict__ We, const void* __restrict__ Wu,
            const void* __restrict__ U3, const void* __restrict__ U2, const void* __restrict__ U1,
            const int* __restrict__ flagp,
            float* __restrict__ Hws, float* __restrict__ U3ws,
            float* __restrict__ U2ws, float* __restrict__ U1ws)
{
  int bf = flagp[0];
  int tid = threadIdx.x;
  for (int t = tid; t < 640; t += 256){
    int z = t >> 6, c = t & 63;
    float s = 0.f;
    for (int k = 0; k < 64; ++k) s += ldf(We, z*64 + k, bf) * ldf(Wu, k*64 + c, bf);
    Hws[t] = s * 0.0395284708f;   // 1/sqrt(Z*C) = 1/sqrt(640)
  }
  for (int t = tid; t < 36; t += 256) U1ws[t] = ldf(U1, t, bf);
  for (int t = tid; t < 45; t += 256){
    int j = 0, rem = t;
    for (;;){ int cnt = 9 - j; if (rem < cnt) break; rem -= cnt; ++j; }
    int k = j + rem;
    for (int p = 0; p < 4; ++p){
      float v = ldf(U2, (j*9 + k)*4 + p, bf);
      if (k > j) v += ldf(U2, (k*9 + j)*4 + p, bf);
      U2ws[t*4 + p] = v;
    }
  }
  for (int t = tid; t < 165; t += 256){
    int i = 0, rem = t;
    for (;;){ int m = 9 - i; int cnt = m*(m+1)/2; if (rem < cnt) break; rem -= cnt; ++i; }
    int j = i;
    for (;;){ int cnt = 9 - j; if (rem < cnt) break; rem -= cnt; ++j; }
    int k = j + rem;
    int pm[6][3] = {{i,j,k},{i,k,j},{j,i,k},{j,k,i},{k,i,j},{k,j,i}};
    float acc[4] = {0,0,0,0};
    for (int m = 0; m < 6; ++m){
      bool dup = false;
      for (int mm = 0; mm < m; ++mm)
        if (pm[mm][0]==pm[m][0] && pm[mm][1]==pm[m][1] && pm[mm][2]==pm[m][2]) dup = true;
      if (!dup){
        int base = ((pm[m][0]*9 + pm[m][1])*9 + pm[m][2])*4;
        for (int p = 0; p < 4; ++p) acc[p] += ldf(U3, base + p, bf);
      }
    }
    for (int p = 0; p < 4; ++p) U3ws[t*4 + p] = acc[p];
  }
}

// ---------------- positions -> float4 ----------------
extern "C" __global__ __launch_bounds__(256)
void k_pos(const void* __restrict__ pos, const int* __restrict__ flagp, float4* __restrict__ posf)
{
  int bf = flagp[0];
  int i = blockIdx.x*256 + threadIdx.x;
  if (i < NN){
    float4 v;
    v.x = ldf(pos, 3*i+0, bf); v.y = ldf(pos, 3*i+1, bf); v.z = ldf(pos, 3*i+2, bf); v.w = 0.f;
    posf[i] = v;
  }
}

// ---------------- CSR build ----------------
extern "C" __global__ __launch_bounds__(256)
void k_deg(const int* __restrict__ eidx, int* __restrict__ deg)
{
  int e = blockIdx.x*256 + threadIdx.x;
  if (e < NE) atomicAdd(&deg[eidx[NE + e]], 1);
}

extern "C" __global__ __launch_bounds__(256)
void k_scan_a(const int* __restrict__ deg, int* __restrict__ bsum)
{
  __shared__ int s[256];
  int tid = threadIdx.x;
  int i = blockIdx.x*256 + tid;
  s[tid] = (i < NN) ? deg[i] : 0;
  __syncthreads();
  for (int d = 128; d > 0; d >>= 1){
    if (tid < d) s[tid] += s[tid + d];
    __syncthreads();
  }
  if (tid == 0) bsum[blockIdx.x] = s[0];
}

extern "C" __global__ __launch_bounds__(128)
void k_scan_b(const int* __restrict__ bsum, int* __restrict__ boff)
{
  __shared__ int s[128];
  int tid = threadIdx.x;
  int v = (tid < 79) ? bsum[tid] : 0;
  s[tid] = v;
  __syncthreads();
  for (int d = 1; d < 128; d <<= 1){
    int t = (tid >= d) ? s[tid - d] : 0;
    __syncthreads();
    s[tid] += t;
    __syncthreads();
  }
  if (tid < 79) boff[tid] = s[tid] - v;
}

extern "C" __global__ __launch_bounds__(256)
void k_scan_c(const int* __restrict__ deg, const int* __restrict__ boff, int* __restrict__ offs)
{
  __shared__ int s[256];
  int tid = threadIdx.x;
  int i = blockIdx.x*256 + tid;
  int v = (i < NN) ? deg[i] : 0;
  s[tid] = v;
  __syncthreads();
  for (int d = 1; d < 256; d <<= 1){
    int t = (tid >= d) ? s[tid - d] : 0;
    __syncthreads();
    s[tid] += t;
    __syncthreads();
  }
  if (i < NN) offs[i] = boff[blockIdx.x] + s[tid] - v;
}

extern "C" __global__ __launch_bounds__(256)
void k_scatter(const int* __restrict__ eidx, const int* __restrict__ offs,
               int* __restrict__ cur, int* __restrict__ elist)
{
  int e = blockIdx.x*256 + threadIdx.x;
  if (e < NE){
    int r = eidx[NE + e];
    int p = atomicAdd(&cur[r], 1);
    elist[offs[r] + p] = e;
  }
}

// ---------------- edge geometry ----------------
__device__ __forceinline__ void edge_geom(float4 pr, float4 ps, float* ef, float* Y)
{
  float vx = pr.x - ps.x, vy = pr.y - ps.y, vz = pr.z - ps.z;
  float r2 = vx*vx + vy*vy + vz*vz + 1e-12f;
  float rinv = rsqrtf(r2);
  float r = r2 * rinv;
  float ux = vx*rinv, uy = vy*rinv, uz = vz*rinv;
  const float s3 = 1.7320508076f, s5 = 2.2360679775f, s15 = 3.8729833462f;
  Y[0] = 1.0f;
  Y[1] = s3*ux; Y[2] = s3*uy; Y[3] = s3*uz;
  Y[4] = s15*ux*uy; Y[5] = s15*uy*uz;
  Y[6] = 0.5f*s5*(3.0f*uz*uz - 1.0f);
  Y[7] = s15*ux*uz;
  Y[8] = 0.5f*s15*(ux*ux - uy*uy);
  float u = r * 0.2f; u = fminf(u, 1.0f);
  float u2 = u*u, u4 = u2*u2, u6 = u4*u2, u7 = u6*u, u8 = u7*u;
  float fc = 1.0f - 28.0f*u6 + 48.0f*u7 - 21.0f*u8;
  float c0 = 0.63245553203f * fc * rinv;     // sqrt(2/RMAX)*fcut/r
  float w = 0.62831853072f * r;              // pi*r/RMAX
  #pragma unroll
  for (int k = 0; k < 8; ++k) ef[k] = c0 * __sinf(w * (float)(k + 1));
}

// ---------------- main fused kernel: gather + MLP + message + contraction + W_out ----------------
extern "C" __global__ __launch_bounds__(256)
void k_main(const int* __restrict__ atom, const int* __restrict__ eidx,
            const void* __restrict__ w1g, const void* __restrict__ w2g,
            const void* __restrict__ w3g, const void* __restrict__ w4g,
            const void* __restrict__ Wc3, const void* __restrict__ Wc2, const void* __restrict__ Wc1,
            const void* __restrict__ Woutg,
            const float* __restrict__ Hws, const float* __restrict__ U3ws,
            const float* __restrict__ U2ws, const float* __restrict__ U1ws,
            const float4* __restrict__ posf,
            const int* __restrict__ deg, const int* __restrict__ offs, const int* __restrict__ elist,
            const int* __restrict__ flagp, void* __restrict__ outp)
{
  __shared__ __align__(16) float w1s[8][64];
  __shared__ __align__(16) u16  w2s[8][64][8];     // [k8][j][k%8]
  __shared__ __align__(16) u16  w3s[8][64][8];
  __shared__ __align__(16) u16  w4s[8][3][64][8];  // [k8][l][c][k%8]
  __shared__ __align__(16) float wos[64][64];
  __shared__ __align__(16) float Hs[10][64];
  __shared__ __align__(16) float U3t[165][4];
  __shared__ __align__(16) float U2t[45][4];
  __shared__ __align__(16) float U1t[9][4];
  __shared__ __align__(16) float fbuf[4][2][64];
  __shared__ int cnts[4];

  int bf = flagp[0];
  int tid = threadIdx.x;
  for (int t = tid; t < 512; t += 256) w1s[t>>6][t&63] = ldf(w1g, t, bf);
  for (int t = tid; t < 4096; t += 256){
    int k = t >> 6, j = t & 63;
    u16 v2 = bf ? ((const u16*)w2g)[t] : f2bf(((const float*)w2g)[t]);
    u16 v3 = bf ? ((const u16*)w3g)[t] : f2bf(((const float*)w3g)[t]);
    w2s[k>>3][j][k&7] = v2;
    w3s[k>>3][j][k&7] = v3;
    wos[k][j] = ldf(Woutg, t, bf);
  }
  for (int t = tid; t < 12288; t += 256){
    int k = t / 192, col = t % 192;
    u16 v4 = bf ? ((const u16*)w4g)[t] : f2bf(((const float*)w4g)[t]);
    w4s[k>>3][col>>6][col&63][k&7] = v4;
  }
  for (int t = tid; t < 640; t += 256) ((float*)Hs)[t]  = Hws[t];
  for (int t = tid; t < 660; t += 256) ((float*)U3t)[t] = U3ws[t];
  for (int t = tid; t < 180; t += 256) ((float*)U2t)[t] = U2ws[t];
  for (int t = tid; t < 36;  t += 256) ((float*)U1t)[t] = U1ws[t];

  int wv = tid >> 6;
  int lane = tid & 63;
  int n = blockIdx.x * 4 + wv;
  int start = offs[n];
  int cnt = deg[n];
  float4 pr = posf[n];
  if (lane == 0) cnts[wv] = cnt;
  __syncthreads();
  int maxcnt = max(max(cnts[0], cnts[1]), max(cnts[2], cnts[3]));

  const float4* fb0 = (const float4*)&fbuf[wv][0][0];
  const float4* fb1 = (const float4*)&fbuf[wv][1][0];

  float X[9];
  #pragma unroll
  for (int m = 0; m < 9; ++m) X[m] = 0.f;

  // Block-uniform trip count: every wave runs maxcnt iterations so that the
  // __syncthreads() inside are legal; out-of-range edges are masked to zero.
  for (int i0 = 0; i0 < maxcnt; i0 += 2){
    bool v0 = (i0 < cnt);         // wave-uniform
    bool v1 = (i0 + 1 < cnt);     // wave-uniform
    int last = (cnt > 0) ? (cnt - 1) : 0;
    int a0i = min(start + min(i0, last),     NE - 1);
    int a1i = min(start + min(i0 + 1, last), NE - 1);
    int e0 = elist[a0i];
    int e1 = elist[a1i];

    int s0 = eidx[e0], s1 = eidx[e1];
    int z0 = atom[s0], z1 = atom[s1];
    float4 ps0 = posf[s0], ps1 = posf[s1];

    float ef0[8], Y0[9], ef1[8], Y1[9];
    edge_geom(pr, ps0, ef0, Y0);
    edge_geom(pr, ps1, ef1, Y1);
    if (!v0){
      #pragma unroll
      for (int k = 0; k < 8; ++k) ef0[k] = 0.f;
      #pragma unroll
      for (int m = 0; m < 9; ++m) Y0[m] = 0.f;
    }
    if (!v1){
      #pragma unroll
      for (int k = 0; k < 8; ++k) ef1[k] = 0.f;
      #pragma unroll
      for (int m = 0; m < 9; ++m) Y1[m] = 0.f;
    }

    // ---- L1: 8 -> 64 ----
    float a0 = 0.f, a1 = 0.f;
    #pragma unroll
    for (int k = 0; k < 8; ++k){
      float wk = w1s[k][lane];
      a0 += ef0[k]*wk; a1 += ef1[k]*wk;
    }
    a0 = silu_f(a0); a1 = silu_f(a1);
    fbuf[wv][0][lane] = a0; fbuf[wv][1][lane] = a1;
    __syncthreads();

    // ---- L2: 64 -> 64 ----
    {
      float pA0=0.f, pA1=0.f, pB0=0.f, pB1=0.f;
      #pragma unroll
      for (int k8 = 0; k8 < 8; ++k8){
        uint4 q = *(const uint4*)&w2s[k8][lane][0];
        float4 fA0 = fb0[2*k8], fA1 = fb0[2*k8+1];
        float4 fB0 = fb1[2*k8], fB1 = fb1[2*k8+1];
        pA0 += bflo(q.x)*fA0.x + bfhi(q.x)*fA0.y + bflo(q.y)*fA0.z + bfhi(q.y)*fA0.w;
        pA1 += bflo(q.z)*fA1.x + bfhi(q.z)*fA1.y + bflo(q.w)*fA1.z + bfhi(q.w)*fA1.w;
        pB0 += bflo(q.x)*fB0.x + bfhi(q.x)*fB0.y + bflo(q.y)*fB0.z + bfhi(q.y)*fB0.w;
        pB1 += bflo(q.z)*fB1.x + bfhi(q.z)*fB1.y + bflo(q.w)*fB1.z + bfhi(q.w)*fB1.w;
      }
      a0 = silu_f(pA0 + pA1); a1 = silu_f(pB0 + pB1);
    }
    __syncthreads();
    fbuf[wv][0][lane] = a0; fbuf[wv][1][lane] = a1;
    __syncthreads();

    // ---- L3: 64 -> 64 ----
    {
      float pA0=0.f, pA1=0.f, pB0=0.f, pB1=0.f;
      #pragma unroll
      for (int k8 = 0; k8 < 8; ++k8){
        uint4 q = *(const uint4*)&w3s[k8][lane][0];
        float4 fA0 = fb0[2*k8], fA1 = fb0[2*k8+1];
        float4 fB0 = fb1[2*k8], fB1 = fb1[2*k8+1];
        pA0 += bflo(q.x)*fA0.x + bfhi(q.x)*fA0.y + bflo(q.y)*fA0.z + bfhi(q.y)*fA0.w;
        pA1 += bflo(q.z)*fA1.x + bfhi(q.z)*fA1.y + bflo(q.w)*fA1.z + bfhi(q.w)*fA1.w;
        pB0 += bflo(q.x)*fB0.x + bfhi(q.x)*fB0.y + bflo(q.y)*fB0.z + bfhi(q.y)*fB0.w;
        pB1 += bflo(q.z)*fB1.x + bfhi(q.z)*fB1.y + bflo(q.w)*fB1.z + bfhi(q.w)*fB1.w;
      }
      a0 = silu_f(pA0 + pA1); a1 = silu_f(pB0 + pB1);
    }
    __syncthreads();
    fbuf[wv][0][lane] = a0; fbuf[wv][1][lane] = a1;
    __syncthreads();

    // ---- L4: 64 -> 192 (tpw[l][c]) ----
    float t0[3] = {0.f,0.f,0.f}, t1[3] = {0.f,0.f,0.f};
    #pragma unroll
    for (int k8 = 0; k8 < 8; ++k8){
      float4 fA0 = fb0[2*k8], fA1 = fb0[2*k8+1];
      float4 fB0 = fb1[2*k8], fB1 = fb1[2*k8+1];
      #pragma unroll
      for (int l = 0; l < 3; ++l){
        uint4 q = *(const uint4*)&w4s[k8][l][lane][0];
        float wa = bflo(q.x), wb = bfhi(q.x), wc = bflo(q.y), wd = bfhi(q.y);
        float we = bflo(q.z), wf = bfhi(q.z), wg = bflo(q.w), wh = bfhi(q.w);
        t0[l] += wa*fA0.x + wb*fA0.y + wc*fA0.z + wd*fA0.w
               + we*fA1.x + wf*fA1.y + wg*fA1.z + wh*fA1.w;
        t1[l] += wa*fB0.x + wb*fB0.y + wc*fB0.z + wd*fB0.w
               + we*fB1.x + wf*fB1.y + wg*fB1.z + wh*fB1.w;
      }
    }
    __syncthreads();   // L4 reads must complete before next iteration overwrites fbuf

    // ---- accumulate messages ----
    float h0 = Hs[z0][lane], h1 = Hs[z1][lane];
    float q00 = h0*t0[0], q01 = h0*t0[1], q02 = h0*t0[2];
    float q10 = h1*t1[0], q11 = h1*t1[1], q12 = h1*t1[2];
    X[0] += q00*Y0[0] + q10*Y1[0];
    X[1] += q01*Y0[1] + q11*Y1[1];
    X[2] += q01*Y0[2] + q11*Y1[2];
    X[3] += q01*Y0[3] + q11*Y1[3];
    X[4] += q02*Y0[4] + q12*Y1[4];
    X[5] += q02*Y0[5] + q12*Y1[5];
    X[6] += q02*Y0[6] + q12*Y1[6];
    X[7] += q02*Y0[7] + q12*Y1[7];
    X[8] += q02*Y0[8] + q12*Y1[8];
  }

  #pragma unroll
  for (int m = 0; m < 9; ++m) X[m] *= 0.0625f;   // / AVG

  // ---- contraction: moments s1, s2, s3 with symmetrized U tables ----
  float s1a[4] = {0,0,0,0}, s2a[4] = {0,0,0,0}, s3a[4] = {0,0,0,0};
  #pragma unroll
  for (int j = 0; j < 9; ++j){
    float4 u = *(const float4*)&U1t[j][0];
    s1a[0] += u.x*X[j]; s1a[1] += u.y*X[j]; s1a[2] += u.z*X[j]; s1a[3] += u.w*X[j];
  }
  {
    int t2 = 0;
    #pragma unroll
    for (int j = 0; j < 9; ++j){
      #pragma unroll
      for (int k = j; k < 9; ++k){
        float m = X[j]*X[k];
        float4 u = *(const float4*)&U2t[t2][0]; ++t2;
        s2a[0] += u.x*m; s2a[1] += u.y*m; s2a[2] += u.z*m; s2a[3] += u.w*m;
      }
    }
  }
  {
    int t3 = 0;
    #pragma unroll
    for (int i = 0; i < 9; ++i){
      #pragma unroll
      for (int j = i; j < 9; ++j){
        float mij = X[i]*X[j];
        #pragma unroll
        for (int k = j; k < 9; ++k){
          float m = mij*X[k];
          float4 u = *(const float4*)&U3t[t3][0]; ++t3;
          s3a[0] += u.x*m; s3a[1] += u.y*m; s3a[2] += u.z*m; s3a[3] += u.w*m;
        }
      }
    }
  }

  int zn = atom[n];
  float outval = 0.f;
  #pragma unroll
  for (int p = 0; p < 4; ++p){
    int base = (zn*4 + p)*64 + lane;
    outval += ldf(Wc1, base, bf)*s1a[p] + ldf(Wc2, base, bf)*s2a[p] + ldf(Wc3, base, bf)*s3a[p];
  }

  // ---- fused final matmul: out[n,c] = (pre[n,:] @ W_out)[c] / 8 ----
  __syncthreads();
  fbuf[wv][0][lane] = outval;
  __syncthreads();
  const float4* pb4 = (const float4*)&fbuf[wv][0][0];
  float acc = 0.f;
  #pragma unroll
  for (int cb = 0; cb < 16; ++cb){
    float4 p = pb4[cb];
    acc += p.x*wos[4*cb+0][lane] + p.y*wos[4*cb+1][lane]
         + p.z*wos[4*cb+2][lane] + p.w*wos[4*cb+3][lane];
  }
  acc *= 0.125f;
  if (bf) ((u16*)outp)[n*64 + lane] = f2bf(acc);
  else    ((float*)outp)[n*64 + lane] = acc;
}

// ---------------- host ----------------
extern "C" void kernel_launch(void* const* d_in, const int* in_sizes, int n_in,
                              void* d_out, int out_size, void* d_ws, size_t ws_size,
                              hipStream_t stream)
{
  const void* pos  = d_in[0];
  const int* atom  = (const int*)d_in[1];
  const int* eidx  = (const int*)d_in[2];
  const void* We   = d_in[3];
  const void* Wu   = d_in[4];
  const void* w1g  = d_in[5];
  const void* w2g  = d_in[6];
  const void* w3g  = d_in[7];
  const void* w4g  = d_in[8];
  const void* U3   = d_in[9];
  const void* U2   = d_in[10];
  const void* U1   = d_in[11];
  const void* Wc3  = d_in[12];
  const void* Wc2  = d_in[13];
  const void* Wc1  = d_in[14];
  const void* Wout = d_in[15];

  char* ws = (char*)d_ws;
  int*    flag  = (int*)(ws + WS_FLAG);
  float*  Hws   = (float*)(ws + WS_H);
  float*  U1ws  = (float*)(ws + WS_U1);
  float*  U2ws  = (float*)(ws + WS_U2);
  float*  U3ws  = (float*)(ws + WS_U3);
  int*    deg   = (int*)(ws + WS_DEG);
  int*    cur   = (int*)(ws + WS_CUR);
  int*    offs  = (int*)(ws + WS_OFF);
  int*    bsum  = (int*)(ws + WS_BSUM);
  int*    boff  = (int*)(ws + WS_BOFF);
  int*    elist = (int*)(ws + WS_ELIST);
  float4* posf  = (float4*)(ws + WS_POSF);

  (void)hipMemsetAsync(ws + WS_DEG, 0, 160000, stream);   // deg + cur

  k_sniff<<<1, 256, 0, stream>>>((const u32*)Wu, flag);
  k_prep<<<1, 256, 0, stream>>>(We, Wu, U3, U2, U1, flag, Hws, U3ws, U2ws, U1ws);
  k_pos<<<79, 256, 0, stream>>>(pos, flag, posf);
  k_deg<<<1250, 256, 0, stream>>>(eidx, deg);
  k_scan_a<<<79, 256, 0, stream>>>(deg, bsum);
  k_scan_b<<<1, 128, 0, stream>>>(bsum, boff);
  k_scan_c<<<79, 256, 0, stream>>>(deg, boff, offs);
  k_scatter<<<1250, 256, 0, stream>>>(eidx, offs, cur, elist);
  k_main<<<5000, 256, 0, stream>>>(atom, eidx, w1g, w2g, w3g, w4g, Wc3, Wc2, Wc1, Wout,
                                   Hws, U3ws, U2ws, U1ws, posf, deg, offs, elist,
                                   flag, d_out);
}

// Round 4
// 1413.184 us; speedup vs baseline: 1.7403x; 1.7403x over previous
//
#include <hip/hip_runtime.h>

typedef unsigned short u16;
typedef unsigned int u32;

#define NN 20000
#define NE 320000

// ---------------- workspace layout (bytes) ---------------- (total ~1.85 MB; Rounds 1-2
// NaN'd with ~7 MB usage -> ws_size is likely ~2 MB, stay under Round-3's footprint)
#define WS_FLAG  0         // 1 i32: 1 = inputs are bf16, 0 = inputs are f32
#define WS_H     256       // 640 f32   H[z][c]
#define WS_U1    3072      // 36  f32
#define WS_U2    3328      // 180 f32   U2sym[45][4]
#define WS_U3    4096      // 660 f32   U3sym[165][4]
#define WS_DEG   7168      // 20000 i32
#define WS_CUR   87168     // 20000 i32 (contiguous after DEG; one memset covers both)
#define WS_OFF   167168    // 20000 i32
#define WS_BSUM  247168    // 79 i32
#define WS_BOFF  247552    // 79 i32
#define WS_ELIST 248064    // 320000 i32
#define WS_POSF  1528064   // 20000 float4

__device__ __forceinline__ float bf2f(u16 u){ return __uint_as_float(((u32)u) << 16); }
__device__ __forceinline__ u16 f2bf(float f){
  u32 u = __float_as_uint(f);
  u32 r = (u + 0x7fffu + ((u >> 16) & 1u)) >> 16;
  return (u16)r;
}
__device__ __forceinline__ float bflo(u32 d){ return __uint_as_float(d << 16); }
__device__ __forceinline__ float bfhi(u32 d){ return __uint_as_float(d & 0xffff0000u); }
__device__ __forceinline__ float silu_f(float v){ return v / (1.0f + __expf(-v)); }

// dtype-agnostic float load: bf=1 -> buffer holds bf16 u16, bf=0 -> f32
__device__ __forceinline__ float ldf(const void* p, int i, int bf){
  return bf ? bf2f(((const u16*)p)[i]) : ((const float*)p)[i];
}

// Wave-synchronous LDS exchange fence: wave64 lanes are lockstep; the
// wave_barrier pins compiler scheduling, the waitcnt drains the DS queue,
// the memory clobber stops reordering/forwarding across it. No s_barrier —
// waves stay fully decoupled (this is the occupancy win vs Round 3).
#define WAVE_SYNC() do { \
  __builtin_amdgcn_wave_barrier(); \
  asm volatile("s_waitcnt lgkmcnt(0)" ::: "memory"); \
  __builtin_amdgcn_wave_barrier(); \
} while (0)

// ---------------- dtype sniffer ----------------
extern "C" __global__ __launch_bounds__(256)
void k_sniff(const u32* __restrict__ wu, int* __restrict__ flag)
{
  __shared__ int s[256];
  int tid = threadIdx.x;
  u32 w = wu[tid];
  u32 e = (w >> 7) & 0xFFu;   // exponent field of the low-half bf16
  s[tid] = (e >= 0x60u && e <= 0x86u) ? 1 : 0;
  __syncthreads();
  for (int d = 128; d > 0; d >>= 1){
    if (tid < d) s[tid] += s[tid + d];
    __syncthreads();
  }
  if (tid == 0) flag[0] = (s[0] > 148) ? 1 : 0;
}

// ---------------- prep: H table + symmetrized U tables ----------------
extern "C" __global__ __launch_bounds__(256)
void k_prep(const void* __restrict__ We, const void* __restrict__ Wu,
            const void* __restrict__ U3, const void* __restrict__ U2, const void* __restrict__ U1,
            const int* __restrict__ flagp,
            float* __restrict__ Hws, float* __restrict__ U3ws,
            float* __restrict__ U2ws, float* __restrict__ U1ws)
{
  int bf = flagp[0];
  int tid = threadIdx.x;
  for (int t = tid; t < 640; t += 256){
    int z = t >> 6, c = t & 63;
    float s = 0.f;
    for (int k = 0; k < 64; ++k) s += ldf(We, z*64 + k, bf) * ldf(Wu, k*64 + c, bf);
    Hws[t] = s * 0.0395284708f;   // 1/sqrt(Z*C) = 1/sqrt(640)
  }
  for (int t = tid; t < 36; t += 256) U1ws[t] = ldf(U1, t, bf);
  for (int t = tid; t < 45; t += 256){
    int j = 0, rem = t;
    for (;;){ int cnt = 9 - j; if (rem < cnt) break; rem -= cnt; ++j; }
    int k = j + rem;
    for (int p = 0; p < 4; ++p){
      float v = ldf(U2, (j*9 + k)*4 + p, bf);
      if (k > j) v += ldf(U2, (k*9 + j)*4 + p, bf);
      U2ws[t*4 + p] = v;
    }
  }
  for (int t = tid; t < 165; t += 256){
    int i = 0, rem = t;
    for (;;){ int m = 9 - i; int cnt = m*(m+1)/2; if (rem < cnt) break; rem -= cnt; ++i; }
    int j = i;
    for (;;){ int cnt = 9 - j; if (rem < cnt) break; rem -= cnt; ++j; }
    int k = j + rem;
    int pm[6][3] = {{i,j,k},{i,k,j},{j,i,k},{j,k,i},{k,i,j},{k,j,i}};
    float acc[4] = {0,0,0,0};
    for (int m = 0; m < 6; ++m){
      bool dup = false;
      for (int mm = 0; mm < m; ++mm)
        if (pm[mm][0]==pm[m][0] && pm[mm][1]==pm[m][1] && pm[mm][2]==pm[m][2]) dup = true;
      if (!dup){
        int base = ((pm[m][0]*9 + pm[m][1])*9 + pm[m][2])*4;
        for (int p = 0; p < 4; ++p) acc[p] += ldf(U3, base + p, bf);
      }
    }
    for (int p = 0; p < 4; ++p) U3ws[t*4 + p] = acc[p];
  }
}

// ---------------- positions -> float4 ----------------
extern "C" __global__ __launch_bounds__(256)
void k_pos(const void* __restrict__ pos, const int* __restrict__ flagp, float4* __restrict__ posf)
{
  int bf = flagp[0];
  int i = blockIdx.x*256 + threadIdx.x;
  if (i < NN){
    float4 v;
    v.x = ldf(pos, 3*i+0, bf); v.y = ldf(pos, 3*i+1, bf); v.z = ldf(pos, 3*i+2, bf); v.w = 0.f;
    posf[i] = v;
  }
}

// ---------------- CSR build ----------------
extern "C" __global__ __launch_bounds__(256)
void k_deg(const int* __restrict__ eidx, int* __restrict__ deg)
{
  int e = blockIdx.x*256 + threadIdx.x;
  if (e < NE) atomicAdd(&deg[eidx[NE + e]], 1);
}

extern "C" __global__ __launch_bounds__(256)
void k_scan_a(const int* __restrict__ deg, int* __restrict__ bsum)
{
  __shared__ int s[256];
  int tid = threadIdx.x;
  int i = blockIdx.x*256 + tid;
  s[tid] = (i < NN) ? deg[i] : 0;
  __syncthreads();
  for (int d = 128; d > 0; d >>= 1){
    if (tid < d) s[tid] += s[tid + d];
    __syncthreads();
  }
  if (tid == 0) bsum[blockIdx.x] = s[0];
}

extern "C" __global__ __launch_bounds__(128)
void k_scan_b(const int* __restrict__ bsum, int* __restrict__ boff)
{
  __shared__ int s[128];
  int tid = threadIdx.x;
  int v = (tid < 79) ? bsum[tid] : 0;
  s[tid] = v;
  __syncthreads();
  for (int d = 1; d < 128; d <<= 1){
    int t = (tid >= d) ? s[tid - d] : 0;
    __syncthreads();
    s[tid] += t;
    __syncthreads();
  }
  if (tid < 79) boff[tid] = s[tid] - v;
}

extern "C" __global__ __launch_bounds__(256)
void k_scan_c(const int* __restrict__ deg, const int* __restrict__ boff, int* __restrict__ offs)
{
  __shared__ int s[256];
  int tid = threadIdx.x;
  int i = blockIdx.x*256 + tid;
  int v = (i < NN) ? deg[i] : 0;
  s[tid] = v;
  __syncthreads();
  for (int d = 1; d < 256; d <<= 1){
    int t = (tid >= d) ? s[tid - d] : 0;
    __syncthreads();
    s[tid] += t;
    __syncthreads();
  }
  if (i < NN) offs[i] = boff[blockIdx.x] + s[tid] - v;
}

extern "C" __global__ __launch_bounds__(256)
void k_scatter(const int* __restrict__ eidx, const int* __restrict__ offs,
               int* __restrict__ cur, int* __restrict__ elist)
{
  int e = blockIdx.x*256 + threadIdx.x;
  if (e < NE){
    int r = eidx[NE + e];
    int p = atomicAdd(&cur[r], 1);
    elist[offs[r] + p] = e;
  }
}

// ---------------- edge geometry ----------------
__device__ __forceinline__ void edge_geom(float4 pr, float4 ps, float* ef, float* Y)
{
  float vx = pr.x - ps.x, vy = pr.y - ps.y, vz = pr.z - ps.z;
  float r2 = vx*vx + vy*vy + vz*vz + 1e-12f;
  float rinv = rsqrtf(r2);
  float r = r2 * rinv;
  float ux = vx*rinv, uy = vy*rinv, uz = vz*rinv;
  const float s3 = 1.7320508076f, s5 = 2.2360679775f, s15 = 3.8729833462f;
  Y[0] = 1.0f;
  Y[1] = s3*ux; Y[2] = s3*uy; Y[3] = s3*uz;
  Y[4] = s15*ux*uy; Y[5] = s15*uy*uz;
  Y[6] = 0.5f*s5*(3.0f*uz*uz - 1.0f);
  Y[7] = s15*ux*uz;
  Y[8] = 0.5f*s15*(ux*ux - uy*uy);
  float u = r * 0.2f; u = fminf(u, 1.0f);
  float u2 = u*u, u4 = u2*u2, u6 = u4*u2, u7 = u6*u, u8 = u7*u;
  float fc = 1.0f - 28.0f*u6 + 48.0f*u7 - 21.0f*u8;
  float c0 = 0.63245553203f * fc * rinv;     // sqrt(2/RMAX)*fcut/r
  float w = 0.62831853072f * r;              // pi*r/RMAX
  #pragma unroll
  for (int k = 0; k < 8; ++k) ef[k] = c0 * __sinf(w * (float)(k + 1));
}

// ---------------- main fused kernel ----------------
// One node per wave; waves fully independent after staging (no barriers in the
// edge loop). LDS 48.9 KB -> 3 blocks/CU; launch_bounds(256,3) caps VGPR<=170.
extern "C" __global__ __launch_bounds__(256, 3)
void k_main(const int* __restrict__ atom, const int* __restrict__ eidx,
            const void* __restrict__ w1g, const void* __restrict__ w2g,
            const void* __restrict__ w3g, const void* __restrict__ w4g,
            const void* __restrict__ Wc3, const void* __restrict__ Wc2, const void* __restrict__ Wc1,
            const void* __restrict__ Woutg,
            const float* __restrict__ Hws, const float* __restrict__ U3ws,
            const float* __restrict__ U2ws, const float* __restrict__ U1ws,
            const float4* __restrict__ posf,
            const int* __restrict__ deg, const int* __restrict__ offs, const int* __restrict__ elist,
            const int* __restrict__ flagp, void* __restrict__ outp)
{
  __shared__ __align__(16) float w1s[8][64];
  __shared__ __align__(16) u16  w2s[8][64][8];     // [k8][j][k%8]
  __shared__ __align__(16) u16  w3s[8][64][8];
  __shared__ __align__(16) u16  w4s[8][3][64][8];  // [k8][l][c][k%8]; reused as f32 W_out at epilogue
  __shared__ __align__(16) float Hs[10][64];
  __shared__ __align__(16) float U3t[165][4];
  __shared__ __align__(16) float U2t[45][4];
  __shared__ __align__(16) float U1t[9][4];
  __shared__ __align__(16) float fbuf[4][64];

  int bf = flagp[0];
  int tid = threadIdx.x;
  for (int t = tid; t < 512; t += 256) w1s[t>>6][t&63] = ldf(w1g, t, bf);
  for (int t = tid; t < 4096; t += 256){
    int k = t >> 6, j = t & 63;
    u16 v2 = bf ? ((const u16*)w2g)[t] : f2bf(((const float*)w2g)[t]);
    u16 v3 = bf ? ((const u16*)w3g)[t] : f2bf(((const float*)w3g)[t]);
    w2s[k>>3][j][k&7] = v2;
    w3s[k>>3][j][k&7] = v3;
  }
  for (int t = tid; t < 12288; t += 256){
    int k = t / 192, col = t % 192;
    u16 v4 = bf ? ((const u16*)w4g)[t] : f2bf(((const float*)w4g)[t]);
    w4s[k>>3][col>>6][col&63][k&7] = v4;
  }
  for (int t = tid; t < 640; t += 256) ((float*)Hs)[t]  = Hws[t];
  for (int t = tid; t < 660; t += 256) ((float*)U3t)[t] = U3ws[t];
  for (int t = tid; t < 180; t += 256) ((float*)U2t)[t] = U2ws[t];
  for (int t = tid; t < 36;  t += 256) ((float*)U1t)[t] = U1ws[t];
  __syncthreads();

  int wv = tid >> 6;
  int lane = tid & 63;
  int n = blockIdx.x * 4 + wv;
  int start = offs[n];
  int cnt = deg[n];
  float4 pr = posf[n];

  const float4* fb = (const float4*)&fbuf[wv][0];

  float X[9];
  #pragma unroll
  for (int m = 0; m < 9; ++m) X[m] = 0.f;

  // Per-wave edge loop: no __syncthreads, no masking, exact trip count.
  for (int i = 0; i < cnt; ++i){
    int e = elist[start + i];
    int s = eidx[e];
    int z = atom[s];
    float4 ps = posf[s];

    float ef[8], Y[9];
    edge_geom(pr, ps, ef, Y);

    // ---- L1: 8 -> 64 ----
    float a = 0.f;
    #pragma unroll
    for (int k = 0; k < 8; ++k) a += ef[k] * w1s[k][lane];
    a = silu_f(a);
    fbuf[wv][lane] = a;
    WAVE_SYNC();

    // ---- L2: 64 -> 64 ----
    {
      float p0 = 0.f, p1 = 0.f;
      #pragma unroll
      for (int k8 = 0; k8 < 8; ++k8){
        uint4 q = *(const uint4*)&w2s[k8][lane][0];
        float4 f0 = fb[2*k8], f1 = fb[2*k8+1];
        p0 += bflo(q.x)*f0.x + bfhi(q.x)*f0.y + bflo(q.y)*f0.z + bfhi(q.y)*f0.w;
        p1 += bflo(q.z)*f1.x + bfhi(q.z)*f1.y + bflo(q.w)*f1.z + bfhi(q.w)*f1.w;
      }
      a = silu_f(p0 + p1);
    }
    WAVE_SYNC();                      // reads drained before overwrite
    fbuf[wv][lane] = a;
    WAVE_SYNC();

    // ---- L3: 64 -> 64 ----
    {
      float p0 = 0.f, p1 = 0.f;
      #pragma unroll
      for (int k8 = 0; k8 < 8; ++k8){
        uint4 q = *(const uint4*)&w3s[k8][lane][0];
        float4 f0 = fb[2*k8], f1 = fb[2*k8+1];
        p0 += bflo(q.x)*f0.x + bfhi(q.x)*f0.y + bflo(q.y)*f0.z + bfhi(q.y)*f0.w;
        p1 += bflo(q.z)*f1.x + bfhi(q.z)*f1.y + bflo(q.w)*f1.z + bfhi(q.w)*f1.w;
      }
      a = silu_f(p0 + p1);
    }
    WAVE_SYNC();
    fbuf[wv][lane] = a;
    WAVE_SYNC();

    // ---- L4: 64 -> 192 (tpw[l][lane]) ----
    float t0 = 0.f, t1 = 0.f, t2 = 0.f;
    #pragma unroll
    for (int k8 = 0; k8 < 8; ++k8){
      float4 f0 = fb[2*k8], f1 = fb[2*k8+1];
      uint4 qa = *(const uint4*)&w4s[k8][0][lane][0];
      t0 += bflo(qa.x)*f0.x + bfhi(qa.x)*f0.y + bflo(qa.y)*f0.z + bfhi(qa.y)*f0.w
          + bflo(qa.z)*f1.x + bfhi(qa.z)*f1.y + bflo(qa.w)*f1.z + bfhi(qa.w)*f1.w;
      uint4 qb = *(const uint4*)&w4s[k8][1][lane][0];
      t1 += bflo(qb.x)*f0.x + bfhi(qb.x)*f0.y + bflo(qb.y)*f0.z + bfhi(qb.y)*f0.w
          + bflo(qb.z)*f1.x + bfhi(qb.z)*f1.y + bflo(qb.w)*f1.z + bfhi(qb.w)*f1.w;
      uint4 qc = *(const uint4*)&w4s[k8][2][lane][0];
      t2 += bflo(qc.x)*f0.x + bfhi(qc.x)*f0.y + bflo(qc.y)*f0.z + bfhi(qc.y)*f0.w
          + bflo(qc.z)*f1.x + bfhi(qc.z)*f1.y + bflo(qc.w)*f1.z + bfhi(qc.w)*f1.w;
    }
    WAVE_SYNC();                      // L4 reads done before next iteration's L1 write

    // ---- accumulate messages ----
    float h = Hs[z][lane];
    float q0 = h*t0, q1 = h*t1, q2 = h*t2;
    X[0] += q0*Y[0];
    X[1] += q1*Y[1]; X[2] += q1*Y[2]; X[3] += q1*Y[3];
    X[4] += q2*Y[4]; X[5] += q2*Y[5]; X[6] += q2*Y[6];
    X[7] += q2*Y[7]; X[8] += q2*Y[8];
  }

  #pragma unroll
  for (int m = 0; m < 9; ++m) X[m] *= 0.0625f;   // / AVG

  // ---- contraction: moments s1, s2, s3 (rolled to keep epilogue VGPRs low) ----
  float s1a[4] = {0,0,0,0}, s2a[4] = {0,0,0,0}, s3a[4] = {0,0,0,0};
  #pragma unroll
  for (int j = 0; j < 9; ++j){
    float4 u = *(const float4*)&U1t[j][0];
    s1a[0] += u.x*X[j]; s1a[1] += u.y*X[j]; s1a[2] += u.z*X[j]; s1a[3] += u.w*X[j];
  }
  {
    int t2i = 0;
    #pragma unroll 1
    for (int j = 0; j < 9; ++j){
      #pragma unroll 1
      for (int k = j; k < 9; ++k){
        float m = X[j]*X[k];
        float4 u = *(const float4*)&U2t[t2i][0]; ++t2i;
        s2a[0] += u.x*m; s2a[1] += u.y*m; s2a[2] += u.z*m; s2a[3] += u.w*m;
      }
    }
  }
  {
    int t3i = 0;
    #pragma unroll 1
    for (int i = 0; i < 9; ++i){
      #pragma unroll 1
      for (int j = i; j < 9; ++j){
        float mij = X[i]*X[j];
        #pragma unroll 1
        for (int k = j; k < 9; ++k){
          float m = mij*X[k];
          float4 u = *(const float4*)&U3t[t3i][0]; ++t3i;
          s3a[0] += u.x*m; s3a[1] += u.y*m; s3a[2] += u.z*m; s3a[3] += u.w*m;
        }
      }
    }
  }

  int zn = atom[n];
  float outval = 0.f;
  #pragma unroll
  for (int p = 0; p < 4; ++p){
    int base = (zn*4 + p)*64 + lane;
    outval += ldf(Wc1, base, bf)*s1a[p] + ldf(Wc2, base, bf)*s2a[p] + ldf(Wc3, base, bf)*s3a[p];
  }

  // ---- fused final matmul: restage W_out (f32) into the w4s LDS region ----
  __syncthreads();                    // all waves done reading w4s
  float* wos = (float*)&w4s[0][0][0][0];   // 16 KB <= 24 KB region
  for (int t = tid; t < 4096; t += 256) wos[t] = ldf(Woutg, t, bf);
  __syncthreads();

  fbuf[wv][lane] = outval;
  WAVE_SYNC();
  float acc = 0.f;
  #pragma unroll
  for (int cb = 0; cb < 16; ++cb){
    float4 p = fb[cb];
    acc += p.x*wos[(4*cb+0)*64 + lane] + p.y*wos[(4*cb+1)*64 + lane]
         + p.z*wos[(4*cb+2)*64 + lane] + p.w*wos[(4*cb+3)*64 + lane];
  }
  acc *= 0.125f;
  if (bf) ((u16*)outp)[n*64 + lane] = f2bf(acc);
  else    ((float*)outp)[n*64 + lane] = acc;
}

// ---------------- host ----------------
extern "C" void kernel_launch(void* const* d_in, const int* in_sizes, int n_in,
                              void* d_out, int out_size, void* d_ws, size_t ws_size,
                              hipStream_t stream)
{
  const void* pos  = d_in[0];
  const int* atom  = (const int*)d_in[1];
  const int* eidx  = (const int*)d_in[2];
  const void* We   = d_in[3];
  const void* Wu   = d_in[4];
  const void* w1g  = d_in[5];
  const void* w2g  = d_in[6];
  const void* w3g  = d_in[7];
  const void* w4g  = d_in[8];
  const void* U3   = d_in[9];
  const void* U2   = d_in[10];
  const void* U1   = d_in[11];
  const void* Wc3  = d_in[12];
  const void* Wc2  = d_in[13];
  const void* Wc1  = d_in[14];
  const void* Wout = d_in[15];

  char* ws = (char*)d_ws;
  int*    flag  = (int*)(ws + WS_FLAG);
  float*  Hws   = (float*)(ws + WS_H);
  float*  U1ws  = (float*)(ws + WS_U1);
  float*  U2ws  = (float*)(ws + WS_U2);
  float*  U3ws  = (float*)(ws + WS_U3);
  int*    deg   = (int*)(ws + WS_DEG);
  int*    cur   = (int*)(ws + WS_CUR);
  int*    offs  = (int*)(ws + WS_OFF);
  int*    bsum  = (int*)(ws + WS_BSUM);
  int*    boff  = (int*)(ws + WS_BOFF);
  int*    elist = (int*)(ws + WS_ELIST);
  float4* posf  = (float4*)(ws + WS_POSF);

  (void)hipMemsetAsync(ws + WS_DEG, 0, 160000, stream);   // deg + cur

  k_sniff<<<1, 256, 0, stream>>>((const u32*)Wu, flag);
  k_prep<<<1, 256, 0, stream>>>(We, Wu, U3, U2, U1, flag, Hws, U3ws, U2ws, U1ws);
  k_pos<<<79, 256, 0, stream>>>(pos, flag, posf);
  k_deg<<<1250, 256, 0, stream>>>(eidx, deg);
  k_scan_a<<<79, 256, 0, stream>>>(deg, bsum);
  k_scan_b<<<1, 128, 0, stream>>>(bsum, boff);
  k_scan_c<<<79, 256, 0, stream>>>(deg, boff, offs);
  k_scatter<<<1250, 256, 0, stream>>>(eidx, offs, cur, elist);
  k_main<<<5000, 256, 0, stream>>>(atom, eidx, w1g, w2g, w3g, w4g, Wc3, Wc2, Wc1, Wout,
                                   Hws, U3ws, U2ws, U1ws, posf, deg, offs, elist,
                                   flag, d_out);
}